// Round 1
// 63.636 us; speedup vs baseline: 1.0082x; 1.0082x over previous
//
#include <hip/hip_runtime.h>
#include <math.h>

#define NF 8
#define HID 128
#define TILE 768   // points per k_main block (4 waves x 12 iters x 16 pts)
#define NIT 12

typedef _Float16 f16;
typedef _Float16 h2 __attribute__((ext_vector_type(2)));
typedef _Float16 f16x8 __attribute__((ext_vector_type(8)));
typedef float f32x4 __attribute__((ext_vector_type(4)));
typedef unsigned int u32;
typedef u32 u32x2 __attribute__((ext_vector_type(2)));
typedef u32 u32x4 __attribute__((ext_vector_type(4)));

__device__ __forceinline__ u32 pk(float a, float b) {
    return __builtin_bit_cast(u32, __builtin_amdgcn_cvt_pkrtz(a, b));
}
__device__ __forceinline__ float dot2a(u32 a, u32 b, float c) {
    return __builtin_amdgcn_fdot2(__builtin_bit_cast(h2, a),
                                  __builtin_bit_cast(h2, b), c, false);
}
__device__ __forceinline__ void lfence() {
    asm volatile("s_waitcnt lgkmcnt(0)" ::: "memory");
}

// ws int layout:
//   [0..7] counts, [8..15] starts, [16..23] tile-prefix, [24] total tiles
//   [32 .. 32+NB*8) per-block counts;  [32+NB*8 ..) perm

__device__ __forceinline__ int assign_field(float px, float py, float pz,
                                            const float* __restrict__ cen) {
    int best = 0;
    float bd = 3.4e38f;
#pragma unroll
    for (int k = 0; k < NF; ++k) {
        float dx = px - cen[k * 3 + 0];
        float dy = py - cen[k * 3 + 1];
        float dz = pz - cen[k * 3 + 2];
        float d = fmaf(dx, dx, fmaf(dy, dy, dz * dz));
        if (d < bd) { bd = d; best = k; }
    }
    return best;
}

// 512 threads, 4 points per thread; per-block counts only (no global atomics).
__global__ void k_count(const float* __restrict__ pos, const float* __restrict__ cen,
                        int n, int* __restrict__ blockcnt) {
    __shared__ int lc[NF];
    int tid = threadIdx.x;
    if (tid < NF) lc[tid] = 0;
    __syncthreads();
    int i4 = blockIdx.x * blockDim.x + tid;
    int base = i4 * 4;
    if (base + 3 < n) {
        const float4* p4 = (const float4*)pos;
        float4 a = p4[i4 * 3 + 0];
        float4 b = p4[i4 * 3 + 1];
        float4 c = p4[i4 * 3 + 2];
        atomicAdd(&lc[assign_field(a.x, a.y, a.z, cen)], 1);
        atomicAdd(&lc[assign_field(a.w, b.x, b.y, cen)], 1);
        atomicAdd(&lc[assign_field(b.z, b.w, c.x, cen)], 1);
        atomicAdd(&lc[assign_field(c.y, c.z, c.w, cen)], 1);
    } else {
        for (int i = base; i < n; ++i)
            atomicAdd(&lc[assign_field(pos[3 * i], pos[3 * i + 1], pos[3 * i + 2], cen)], 1);
    }
    __syncthreads();
    if (tid < NF) blockcnt[blockIdx.x * NF + tid] = lc[tid];
}

// Fused scan+scatter: every block redundantly scans the (nb x 8) count table
// (2 KB from L2), derives its own write offsets, then scatters its 4-pt chunk.
// Block 0 also writes the ws header. 512 threads; wave f owns field f in scan.
__global__ void k_scatscan(const float* __restrict__ pos, const float* __restrict__ cen,
                           int n, int nb, int* __restrict__ ws) {
    const int tid = threadIdx.x;
    const int f = tid >> 6, lane = tid & 63;
    const int* c = ws + 32;
    int* perm = ws + 32 + nb * NF;
    __shared__ int totals[NF], pres[NF], starts[NF], cur[NF];

    int tot = 0, pre = 0;
    for (int b = lane; b < nb; b += 64) {
        int v = c[b * NF + f];
        tot += v;
        if (b < (int)blockIdx.x) pre += v;
    }
#pragma unroll
    for (int d = 1; d < 64; d <<= 1) {
        tot += __shfl_xor(tot, d, 64);
        pre += __shfl_xor(pre, d, 64);
    }
    if (lane == 0) { totals[f] = tot; pres[f] = pre; }
    __syncthreads();
    if (tid == 0) {
        int s = 0, tp = 0;
        for (int k = 0; k < NF; ++k) {
            starts[k] = s;
            if (blockIdx.x == 0) {
                ws[k] = totals[k];
                ws[8 + k] = s;
                ws[16 + k] = tp;
            }
            s += totals[k];
            tp += (totals[k] + TILE - 1) / TILE;
        }
        if (blockIdx.x == 0) ws[24] = tp;
    }
    __syncthreads();
    if (tid < NF) cur[tid] = starts[tid] + pres[tid];
    __syncthreads();

    int i4 = blockIdx.x * blockDim.x + tid;
    int base = i4 * 4;
    if (base + 3 < n) {
        const float4* p4 = (const float4*)pos;
        float4 a = p4[i4 * 3 + 0];
        float4 b = p4[i4 * 3 + 1];
        float4 cc = p4[i4 * 3 + 2];
        int f0 = assign_field(a.x, a.y, a.z, cen);
        int f1 = assign_field(a.w, b.x, b.y, cen);
        int f2 = assign_field(b.z, b.w, cc.x, cen);
        int f3 = assign_field(cc.y, cc.z, cc.w, cen);
        perm[atomicAdd(&cur[f0], 1)] = base;
        perm[atomicAdd(&cur[f1], 1)] = base + 1;
        perm[atomicAdd(&cur[f2], 1)] = base + 2;
        perm[atomicAdd(&cur[f3], 1)] = base + 3;
    } else {
        for (int i = base; i < n; ++i) {
            int ff = assign_field(pos[3 * i], pos[3 * i + 1], pos[3 * i + 2], cen);
            perm[atomicAdd(&cur[ff], 1)] = i;
        }
    }
}

// Clamped perm-index load for iteration IT (statement expression, all-register).
#define LDPERM(IT)                                                            \
    ({                                                                        \
        int _plc = tstart + (IT) * 64 + w * 16 + pt;                          \
        if (_plc > cnt - 1) _plc = cnt - 1;                                   \
        perm[start + _plc];                                                   \
    })

// Issue the gather for iteration IT2 into the named buffer registers.
// quad0: pos (3 dwords), quad3: dir (3 dwords), quad1/2: app halves (4x16B).
#define GATHER(IT2, PX, PY, PZ, D0, D1, D2, A0, A1, A2, A3, GI)               \
    {                                                                         \
        const int _nb = tstart + (IT2) * 64 + w * 16;                         \
        if ((IT2) < NIT && _nb < cnt) {                                       \
            if (quad == 0) {                                                  \
                PX = positions[(GI) * 3 + 0];                                 \
                PY = positions[(GI) * 3 + 1];                                 \
                PZ = positions[(GI) * 3 + 2];                                 \
            } else if (quad == 3) {                                           \
                D0 = directions[(GI) * 3 + 0];                                \
                D1 = directions[(GI) * 3 + 1];                                \
                D2 = directions[(GI) * 3 + 2];                                \
            } else {                                                          \
                const float4* _ap = (const float4*)(app + (GI) * 32) +        \
                                    (quad == 2 ? 4 : 0);                      \
                A0 = _ap[0]; A1 = _ap[1]; A2 = _ap[2]; A3 = _ap[3];           \
            }                                                                 \
        }                                                                     \
    }

// Stage buffer registers into LDS (sCin / sIdx).
#define STAGE(PX, PY, PZ, D0, D1, D2, A0, A1, A2, A3, CI)                     \
    {                                                                         \
        if (quad == 0) {                                                      \
            sIdx[w][pt] = (CI);                                               \
        } else if (quad == 3) {                                               \
            u32x2 _d; _d.x = pk(D0, D1); _d.y = pk(D2, 1.f);                  \
            *(u32x2*)&sCin[w][pt * 72] = _d;                                  \
        } else if (quad == 1) {                                               \
            u32x4 _v0, _v1;                                                   \
            _v0.x = pk(A0.x, A0.y); _v0.y = pk(A0.z, A0.w);                   \
            _v0.z = pk(A1.x, A1.y); _v0.w = pk(A1.z, A1.w);                   \
            _v1.x = pk(A2.x, A2.y); _v1.y = pk(A2.z, A2.w);                   \
            _v1.z = pk(A3.x, A3.y); _v1.w = pk(A3.z, A3.w);                   \
            *(u32x4*)&sCin[w][pt * 72 + 8] = _v0;                             \
            *(u32x4*)&sCin[w][pt * 72 + 16] = _v1;                            \
        } else {                                                              \
            u32x4 _v0, _v1;                                                   \
            _v0.x = pk(A0.x, A0.y); _v0.y = pk(A0.z, A0.w);                   \
            _v0.z = pk(A1.x, A1.y); _v0.w = pk(A1.z, A1.w);                   \
            _v1.x = pk(A2.x, A2.y); _v1.y = pk(A2.z, A2.w);                   \
            _v1.z = pk(A3.x, A3.y); _v1.w = pk(A3.z, A3.w);                   \
            *(u32x4*)&sCin[w][pt * 72 + 24] = _v0;                            \
            *(u32x4*)&sCin[w][pt * 72 + 32] = _v1;                           \
        }                                                                     \
    }

// L1 -> L2 -> L3+L4 for the current iteration (unchanged math).
#define COMPUTE(CI, X01, X23)                                                 \
    {                                                                         \
        u32x4 _xv; _xv.x = (X01); _xv.y = (X23); _xv.z = 0u; _xv.w = 0u;      \
        const f16x8 _xb = __builtin_bit_cast(f16x8, _xv);                     \
        _Pragma("unroll")                                                     \
        for (int mt = 0; mt < 8; ++mt) {                                      \
            u32x4 _av; _av.x = wd1a0[mt]; _av.y = wd1a1[mt];                  \
            _av.z = 0u; _av.w = 0u;                                           \
            f16x8 _af = __builtin_bit_cast(f16x8, _av);                       \
            f32x4 _acc = {0.f, 0.f, 0.f, 0.f};                                \
            _acc = __builtin_amdgcn_mfma_f32_16x16x32_f16(_af, _xb, _acc, 0, 0, 0); \
            u32x2 _hw;                                                        \
            _hw.x = pk(fmaxf(_acc[0], 0.f), fmaxf(_acc[1], 0.f));             \
            _hw.y = pk(fmaxf(_acc[2], 0.f), fmaxf(_acc[3], 0.f));             \
            *(u32x2*)&sH[w][pt * 136 + 16 * mt + quad * 4] = _hw;             \
        }                                                                     \
        lfence();                                                             \
        f32x4 _dacc = {bd2v, bd2v, bd2v, bd2v};                               \
        _Pragma("unroll")                                                     \
        for (int s = 0; s < 4; ++s) {                                         \
            f16x8 _ha = __builtin_bit_cast(f16x8,                             \
                *(const u32x4*)&sH[w][pt * 136 + quad * 8 + 32 * s]);         \
            _dacc = __builtin_amdgcn_mfma_f32_16x16x32_f16(_ha, wd2b[s], _dacc, 0, 0, 0); \
        }                                                                     \
        if (pt == 0) {                                                        \
            int4 _si = *(const int4*)&sIdx[w][quad * 4];                      \
            out[_si.x * 4] = __expf(_dacc[0]);                                \
            out[_si.y * 4] = __expf(_dacc[1]);                                \
            out[_si.z * 4] = __expf(_dacc[2]);                                \
            out[_si.w * 4] = __expf(_dacc[3]);                                \
        } else {                                                              \
            _Pragma("unroll")                                                 \
            for (int r = 0; r < 4; ++r)                                       \
                sCin[w][(quad * 4 + r) * 72 + 40 + (pt - 1)] = (f16)_dacc[r]; \
        }                                                                     \
        lfence();                                                             \
        const f16x8 _cb0 = __builtin_bit_cast(f16x8,                          \
            *(const u32x4*)&sCin[w][pt * 72 + quad * 8]);                     \
        const f16x8 _cb1 = __builtin_bit_cast(f16x8,                          \
            *(const u32x4*)&sCin[w][pt * 72 + quad * 8 + 32]);                \
        float _r0 = 0.f, _r1 = 0.f, _r2 = 0.f;                                \
        _Pragma("unroll")                                                     \
        for (int mt = 0; mt < 8; ++mt) {                                      \
            f16x8 _wa0 = __builtin_bit_cast(f16x8,                            \
                *(const u32x4*)&sWc1t[(16 * mt + pt) * 72 + quad * 8]);       \
            f16x8 _wa1 = __builtin_bit_cast(f16x8,                            \
                *(const u32x4*)&sWc1t[(16 * mt + pt) * 72 + quad * 8 + 32]);  \
            f32x4 _cacc = {0.f, 0.f, 0.f, 0.f};                               \
            _cacc = __builtin_amdgcn_mfma_f32_16x16x32_f16(_wa0, _cb0, _cacc, 0, 0, 0); \
            _cacc = __builtin_amdgcn_mfma_f32_16x16x32_f16(_wa1, _cb1, _cacc, 0, 0, 0); \
            u32 _h01 = pk(fmaxf(_cacc[0], 0.f), fmaxf(_cacc[1], 0.f));        \
            u32 _h23 = pk(fmaxf(_cacc[2], 0.f), fmaxf(_cacc[3], 0.f));        \
            u32x4 _w01 = *(const u32x4*)&sWc2p[(8 * mt + 2 * quad) * 4];      \
            u32x4 _w23 = *(const u32x4*)&sWc2p[(8 * mt + 2 * quad + 1) * 4];  \
            _r0 = dot2a(_h01, _w01.x, _r0); _r0 = dot2a(_h23, _w23.x, _r0);   \
            _r1 = dot2a(_h01, _w01.y, _r1); _r1 = dot2a(_h23, _w23.y, _r1);   \
            _r2 = dot2a(_h01, _w01.z, _r2); _r2 = dot2a(_h23, _w23.z, _r2);   \
        }                                                                     \
        _r0 += __shfl_xor(_r0, 16, 64); _r0 += __shfl_xor(_r0, 32, 64);       \
        _r1 += __shfl_xor(_r1, 16, 64); _r1 += __shfl_xor(_r1, 32, 64);       \
        _r2 += __shfl_xor(_r2, 16, 64); _r2 += __shfl_xor(_r2, 32, 64);       \
        if (quad == 0) {                                                      \
            float _s0 = 1.f / (1.f + __expf(-(_r0 + c20)));                   \
            float _s1 = 1.f / (1.f + __expf(-(_r1 + c21)));                   \
            float _s2 = 1.f / (1.f + __expf(-(_r2 + c22)));                   \
            out[(CI) * 4 + 1] = _s0;                                          \
            *(float2*)&out[(CI) * 4 + 2] = make_float2(_s1, _s2);             \
        }                                                                     \
    }

// One pipelined iteration: stage buffer -> reissue gather 2 ahead -> compute.
#define HALF(IT, PX, PY, PZ, D0, D1, D2, A0, A1, A2, A3, IDX, NIDX)           \
    {                                                                         \
        lfence(); /* prior iter's LDS reads done before sCin overwrite */     \
        STAGE(PX, PY, PZ, D0, D1, D2, A0, A1, A2, A3, IDX);                   \
        const u32 _x01 = (quad == 0) ? pk(PX, PY) : 0u;                       \
        const u32 _x23 = (quad == 0) ? pk(PZ, 1.f) : 0u;                      \
        const int _ci = IDX;                                                  \
        GATHER((IT) + 2, PX, PY, PZ, D0, D1, D2, A0, A1, A2, A3, NIDX);       \
        IDX = NIDX;                                                           \
        if ((IT) + 4 < NIT) NIDX = LDPERM((IT) + 4);                          \
        lfence(); /* sCin staging visible before L3 reads */                  \
        COMPUTE(_ci, _x01, _x23);                                             \
    }

// MFMA k_main with depth-2 data prefetch and depth-4 perm-index prefetch.
// cin layout per point (72 halves): [0..2]=dir, [3]=1(bias), [4..7]=0,
// [8..39]=app, [40..54]=geo, [55..63]=0. Wc1^T staged to match.
__global__ __launch_bounds__(256, 3) void k_main(
    const float* __restrict__ positions, const float* __restrict__ directions,
    const float* __restrict__ app,
    const float* __restrict__ Wd1, const float* __restrict__ bd1,
    const float* __restrict__ Wd2, const float* __restrict__ bd2,
    const float* __restrict__ Wc1, const float* __restrict__ bc1,
    const float* __restrict__ Wc2, const float* __restrict__ bc2,
    const int* __restrict__ ws, int nb, float* __restrict__ out) {
    const int b = blockIdx.x;
    if (b >= ws[24]) return;
    int f = 0;
#pragma unroll
    for (int k = 1; k < NF; ++k) if (b >= ws[16 + k]) f = k;
    const int tile = b - ws[16 + f];
    const int cnt = ws[f];
    const int start = ws[8 + f];
    const int* perm = ws + 32 + nb * NF;
    const int tid = threadIdx.x;
    const int w = tid >> 6, lane = tid & 63;
    const int pt = lane & 15, quad = lane >> 4;

    __shared__ __align__(16) f16 sWc1t[HID * 72];   // [h][72] permuted    18 KB
    __shared__ __align__(16) u32 sWc2p[64 * 4];     // [hp][ch] h2 pairs    1 KB
    __shared__ __align__(16) int sIdx[4][16];
    __shared__ __align__(16) f16 sCin[4][16 * 72];  // per-wave             9 KB
    __shared__ __align__(16) f16 sH[4][16 * 136];   // per-wave            17 KB

    // ---- stage Wc1^T (permuted, f16) and Wc2 pairs ----
    if (tid < HID) {
        int h = tid;
        f16* row = &sWc1t[h * 72];
        const float* Wf = Wc1 + f * 50 * HID;
        row[0] = (f16)Wf[0 * HID + h];
        row[1] = (f16)Wf[1 * HID + h];
        row[2] = (f16)Wf[2 * HID + h];
        row[3] = (f16)bc1[f * HID + h];
        row[4] = 0; row[5] = 0; row[6] = 0; row[7] = 0;
        for (int a = 0; a < 32; ++a) row[8 + a] = (f16)Wf[(18 + a) * HID + h];
        for (int g = 0; g < 15; ++g) row[40 + g] = (f16)Wf[(3 + g) * HID + h];
        for (int z = 55; z < 72; ++z) row[z] = 0;
    }
    if (tid < 64) {
        int hp = tid;
        const float* W2 = Wc2 + f * HID * 3;
        sWc2p[hp * 4 + 0] = pk(W2[(2 * hp) * 3 + 0], W2[(2 * hp + 1) * 3 + 0]);
        sWc2p[hp * 4 + 1] = pk(W2[(2 * hp) * 3 + 1], W2[(2 * hp + 1) * 3 + 1]);
        sWc2p[hp * 4 + 2] = pk(W2[(2 * hp) * 3 + 2], W2[(2 * hp + 1) * 3 + 2]);
        sWc2p[hp * 4 + 3] = 0;
    }
    if (lane < 16) {  // zero cin pad zones (per-wave region)
        f16* row = &sCin[w][pt * 72];
        u32x2 z2; z2.x = 0; z2.y = 0;
        *(u32x2*)&row[4] = z2;
        row[55] = 0;
        u32x4 z4; z4.x = 0; z4.y = 0; z4.z = 0; z4.w = 0;
        *(u32x4*)&row[56] = z4;
    }

    // ---- resident fragments (from global) ----
    u32 wd1a0[8], wd1a1[8];
    if (quad == 0) {
        const float* W1 = Wd1 + f * 3 * HID;
        const float* B1 = bd1 + f * HID;
#pragma unroll
        for (int mt = 0; mt < 8; ++mt) {
            int m = 16 * mt + pt;
            wd1a0[mt] = pk(W1[m], W1[HID + m]);
            wd1a1[mt] = pk(W1[2 * HID + m], B1[m]);
        }
    } else {
#pragma unroll
        for (int mt = 0; mt < 8; ++mt) { wd1a0[mt] = 0; wd1a1[mt] = 0; }
    }
    f16x8 wd2b[4];
    {
        const float* W2d = Wd2 + f * HID * 16;
#pragma unroll
        for (int s = 0; s < 4; ++s) {
            u32x4 v;
#pragma unroll
            for (int jp = 0; jp < 4; ++jp) {
                int k = quad * 8 + 32 * s + 2 * jp;
                v[jp] = pk(W2d[k * 16 + pt], W2d[(k + 1) * 16 + pt]);
            }
            wd2b[s] = __builtin_bit_cast(f16x8, v);
        }
    }
    const float bd2v = bd2[f * 16 + pt];
    const float c20 = bc2[f * 3 + 0], c21 = bc2[f * 3 + 1], c22 = bc2[f * 3 + 2];
    __syncthreads();

    const int tstart = tile * TILE;

    // ---- pipelined gather state ----
    // idxA/idxB: indices whose DATA is in buffers A/B (iters it, it+1).
    // nidxA/nidxB: indices for iters it+2, it+3 (addresses prefetched).
    float pxa, pya, pza, d0a, d1a, d2a;
    float4 a0a, a1a, a2a, a3a;
    float pxb, pyb, pzb, d0b, d1b, d2b;
    float4 a0b, a1b, a2b, a3b;

    int idxA = LDPERM(0);
    int idxB = LDPERM(1);
    GATHER(0, pxa, pya, pza, d0a, d1a, d2a, a0a, a1a, a2a, a3a, idxA);
    GATHER(1, pxb, pyb, pzb, d0b, d1b, d2b, a0b, a1b, a2b, a3b, idxB);
    int nidxA = LDPERM(2);
    int nidxB = LDPERM(3);

#pragma unroll 1
    for (int it = 0; it < NIT; it += 2) {
        if (tstart + it * 64 + w * 16 >= cnt) break;
        HALF(it, pxa, pya, pza, d0a, d1a, d2a, a0a, a1a, a2a, a3a, idxA, nidxA);
        if (tstart + (it + 1) * 64 + w * 16 >= cnt) break;
        HALF(it + 1, pxb, pyb, pzb, d0b, d1b, d2b, a0b, a1b, a2b, a3b, idxB, nidxB);
    }
}

extern "C" void kernel_launch(void* const* d_in, const int* in_sizes, int n_in,
                              void* d_out, int out_size, void* d_ws, size_t ws_size,
                              hipStream_t stream) {
    const float* positions = (const float*)d_in[0];
    const float* directions = (const float*)d_in[1];
    const float* app = (const float*)d_in[2];
    const float* centroids = (const float*)d_in[3];
    const float* Wd1 = (const float*)d_in[4];
    const float* bd1 = (const float*)d_in[5];
    const float* Wd2 = (const float*)d_in[6];
    const float* bd2 = (const float*)d_in[7];
    const float* Wc1 = (const float*)d_in[8];
    const float* bc1 = (const float*)d_in[9];
    const float* Wc2 = (const float*)d_in[10];
    const float* bc2 = (const float*)d_in[11];
    float* out = (float*)d_out;
    int* wsi = (int*)d_ws;
    const int n = in_sizes[0] / 3;
    const int nb = (n + 2047) / 2048;   // 512 threads x 4 pts
    const int max_tiles = (n + TILE - 1) / TILE + NF;

    k_count<<<nb, 512, 0, stream>>>(positions, centroids, n, wsi + 32);
    k_scatscan<<<nb, 512, 0, stream>>>(positions, centroids, n, nb, wsi);
    k_main<<<max_tiles, 256, 0, stream>>>(positions, directions, app, Wd1, bd1, Wd2,
                                          bd2, Wc1, bc1, Wc2, bc2, wsi, nb, out);
}